// Round 9
// baseline (90.338 us; speedup 1.0000x reference)
//
#include <hip/hip_runtime.h>

// DisjointDense: out[b] = x[b] @ W[sel[b]] + Bw[sel[b]]
// B=4096, D_IN=256, D_OUT=256, N_DISJOINT=64, all fp32.
//
// R9 (over R8): two dispatches only.
//  - dd_prep zeroes counts itself via atomicCAS(0xAAAAAAAA -> 0): the harness
//    re-poisons d_ws to 0xAA before every launch; a 0 start also works (CAS
//    no-ops). Per-address atomic total order makes this race-free. Memset
//    dispatch eliminated.
//  - dd_prep at 256 blocks x 16 rows (was 128x32): halves the per-block
//    latency chain; same global-atomic pressure (~56/line).
//  - dd_compute grid 512 [rt:2][ct:4][d:64], row stride 64 (was 1024/stride
//    128 where rt=3 blocks were all dead): B-fragment prologue (64 strided W
//    loads) amortized over ~1.5 row-iterations, W L2 traffic halved.

#define NBLK 64
#define BCAP 1024
#define CPAD 16
#define POISON 0xAAAAAAAAu

typedef __attribute__((ext_vector_type(8))) short bf16x8;
typedef __attribute__((ext_vector_type(4))) float f32x4;

__device__ __forceinline__ unsigned short f2bf(float f) {
    unsigned u = __float_as_uint(f);
    u += 0x7FFFu + ((u >> 16) & 1u);       // round-to-nearest-even
    return (unsigned short)(u >> 16);
}

// 256 blocks x 256 threads; block handles 16 rows: bucketize + x->bf16.
__global__ __launch_bounds__(256) void dd_prep(
    const float* __restrict__ x,        // [4096, 256]
    const float* __restrict__ onehot,   // [4096, 64]
    unsigned int* __restrict__ counts,  // [64*CPAD], poison-initialized
    int* __restrict__ buckets,          // [64, BCAP]
    unsigned short* __restrict__ xb)    // [4096, 256] bf16
{
    __shared__ int rowd[16];
    __shared__ int lhist[NBLK];
    __shared__ int lbase[NBLK];
    const int t = threadIdx.x;
    const int w = t >> 6;
    const int lane = t & 63;

    // fire the poison->0 CAS early (exactly one succeeds per counter; every
    // block's own CAS precedes its own add below, so counts are zeroed
    // before any increment lands).
    if (t < NBLK) atomicCAS(&counts[t * CPAD], POISON, 0u);
    if (t < NBLK) lhist[t] = 0;

    const int row0 = blockIdx.x * 16;
    // wave w: ballots for rows w*4 .. w*4+3
#pragma unroll
    for (int i = 0; i < 4; ++i) {
        const int row = row0 + w * 4 + i;
        const float v = onehot[(size_t)row * NBLK + lane];   // coalesced 256B
        const unsigned long long mm = __ballot(v > 0.5f);
        const int d = (int)__ffsll(mm) - 1;
        if (lane == 0) rowd[w * 4 + i] = d;
    }
    // wave w: x->bf16 for rows w*4 .. w*4+3, 1 float4/lane/row
#pragma unroll
    for (int i = 0; i < 4; ++i) {
        const int row = row0 + w * 4 + i;
        const float4 v = ((const float4*)(x + ((size_t)row << 8)))[lane];
        ushort4 b;
        b.x = f2bf(v.x); b.y = f2bf(v.y); b.z = f2bf(v.z); b.w = f2bf(v.w);
        *(ushort4*)(xb + ((size_t)row << 8) + lane * 4) = b;  // 512B/row contiguous
    }
    __syncthreads();

    int d = 0, slot = 0;
    if (t < 16) {
        d = rowd[t];
        slot = atomicAdd(&lhist[d], 1);        // LDS atomic
    }
    __syncthreads();
    if (t < NBLK && lhist[t] > 0)              // skip zero increments
        lbase[t] = (int)atomicAdd(&counts[t * CPAD], (unsigned)lhist[t]);
    __syncthreads();
    if (t < 16) buckets[d * BCAP + lbase[d] + slot] = row0 + t;
}

// 512 blocks: [task:3][d:6], d = blockIdx&63 (XCD affinity).
// task = rt*4+ct; rt in {0,1} (row-tile base rt*32, stride 64), ct in 0..3.
// Block tile: 32 bucket-rows x 64 cols; 4 waves = 4 col-slices of 16.
// No LDS, no barriers.
__global__ __launch_bounds__(256) void dd_compute(
    const unsigned short* __restrict__ xb,    // [4096, 256] bf16
    const float* __restrict__ W,              // [64, 256, 256] (d, k, col)
    const float* __restrict__ Bw,             // [64, 256]
    const unsigned int* __restrict__ counts,  // [64*CPAD]
    const int* __restrict__ buckets,          // [64, BCAP]
    float* __restrict__ out)                  // [4096, 256]
{
    const int t    = threadIdx.x;
    const int lane = t & 63;
    const int w    = t >> 6;                  // wave = col-slice
    const int d    = blockIdx.x & 63;
    const int task = blockIdx.x >> 6;         // 0..7
    const int rt   = task >> 2;               // 0..1
    const int ct   = task & 3;                // 0..3
    const int cw   = ct * 64 + w * 16;        // wave's col base
    const int m    = lane & 15;
    const int qd   = lane >> 4;

    const int cnt = (int)counts[d * CPAD];
    if (rt * 32 >= cnt) return;               // early exit before W prologue

    // loop-invariant B fragments straight from fp32 W:
    // lane holds B[k=kb*32+qd*8+j][n=cw+m]
    const float* wb = W + ((size_t)d << 16) + (size_t)(qd * 8) * 256 + (cw + m);
    bf16x8 bfrag[8];
#pragma unroll
    for (int kb = 0; kb < 8; ++kb) {
        const float* wp = wb + (size_t)(kb * 32) * 256;
#pragma unroll
        for (int j = 0; j < 8; ++j)
            bfrag[kb][j] = (short)f2bf(wp[j * 256]);
    }

    const float bias = Bw[d * 256 + cw + m];
    const int* bkt = buckets + d * BCAP;

    for (int base = rt * 32; base < cnt; base += 64) {
        // per-lane row-id gathers (16 consecutive slots -> 1-2 lines)
        const int i0 = base + m;
        const int i1 = base + 16 + m;
        const int r0 = bkt[i0 < cnt ? i0 : cnt - 1];
        const int r1 = bkt[i1 < cnt ? i1 : cnt - 1];

        // A fragments: direct 16B bf16 loads, rows r0/r1, k = kb*32 + qd*8
        const unsigned short* xp0 = xb + ((size_t)r0 << 8) + qd * 8;
        const unsigned short* xp1 = xb + ((size_t)r1 << 8) + qd * 8;

        f32x4 acc0 = {bias, bias, bias, bias};
        f32x4 acc1 = {bias, bias, bias, bias};
#pragma unroll
        for (int kb = 0; kb < 8; ++kb) {
            bf16x8 a0 = *(const bf16x8*)(xp0 + kb * 32);
            acc0 = __builtin_amdgcn_mfma_f32_16x16x32_bf16(a0, bfrag[kb], acc0, 0, 0, 0);
        }
#pragma unroll
        for (int kb = 0; kb < 8; ++kb) {
            bf16x8 a1 = *(const bf16x8*)(xp1 + kb * 32);
            acc1 = __builtin_amdgcn_mfma_f32_16x16x32_bf16(a1, bfrag[kb], acc1, 0, 0, 0);
        }

        // stores: C/D row = qd*4+reg, col = m; re-gather rids (L1-hot)
#pragma unroll
        for (int reg = 0; reg < 4; ++reg) {
            const int rl0 = base + qd * 4 + reg;
            if (rl0 < cnt) {
                const int rr = bkt[rl0];
                out[((size_t)rr << 8) + cw + m] = acc0[reg];
            }
            const int rl1 = base + 16 + qd * 4 + reg;
            if (rl1 < cnt) {
                const int rr = bkt[rl1];
                out[((size_t)rr << 8) + cw + m] = acc1[reg];
            }
        }
    }
}

extern "C" void kernel_launch(void* const* d_in, const int* in_sizes, int n_in,
                              void* d_out, int out_size, void* d_ws, size_t ws_size,
                              hipStream_t stream) {
    const float* x      = (const float*)d_in[0];   // [4096, 256]
    const float* onehot = (const float*)d_in[1];   // [4096, 64]
    const float* W      = (const float*)d_in[2];   // [64, 256, 256]
    const float* Bw     = (const float*)d_in[3];   // [64, 256]
    float* out = (float*)d_out;                    // [4096, 256]

    // ws layout: counts 4KB | buckets 256KB | xb 2MB
    unsigned int* counts = (unsigned int*)d_ws;
    int* buckets = (int*)((char*)d_ws + NBLK * CPAD * 4);
    unsigned short* xb = (unsigned short*)((char*)d_ws + NBLK * CPAD * 4 + NBLK * BCAP * 4);

    dd_prep<<<256, 256, 0, stream>>>(x, onehot, counts, buckets, xb);
    dd_compute<<<512, 256, 0, stream>>>(xb, W, Bw, counts, buckets, out);
}

// Round 10
// 88.465 us; speedup vs baseline: 1.0212x; 1.0212x over previous
//
#include <hip/hip_runtime.h>

// DisjointDense: out[b] = x[b] @ W[sel[b]] + Bw[sel[b]]
// B=4096, D_IN=256, D_OUT=256, N_DISJOINT=64, all fp32.
//
// R10 = R8 structure (proven 85.9us) + R9's dd_compute 512-grid (the one
// theoretically-sound change). R9's atomicCAS counts-zeroing regressed +4.4us
// (16K device-scope CAS on 64 lines = cross-XCD serialization, same failure
// mode as R1/R2) -- reverted to the 4KB memset dispatch. dd_prep back to
// 128 blocks x 32 rows (R8-measured).

#define NBLK 64
#define BCAP 1024
#define CPAD 16

typedef __attribute__((ext_vector_type(8))) short bf16x8;
typedef __attribute__((ext_vector_type(4))) float f32x4;

__device__ __forceinline__ unsigned short f2bf(float f) {
    unsigned u = __float_as_uint(f);
    u += 0x7FFFu + ((u >> 16) & 1u);       // round-to-nearest-even
    return (unsigned short)(u >> 16);
}

// 128 blocks x 256 threads; block handles 32 rows: bucketize + x->bf16.
__global__ __launch_bounds__(256) void dd_prep(
    const float* __restrict__ x,        // [4096, 256]
    const float* __restrict__ onehot,   // [4096, 64]
    int* __restrict__ counts,           // [64*CPAD], pre-zeroed
    int* __restrict__ buckets,          // [64, BCAP]
    unsigned short* __restrict__ xb)    // [4096, 256] bf16
{
    __shared__ int rowd[32];
    __shared__ int lhist[NBLK];
    __shared__ int lbase[NBLK];
    const int t = threadIdx.x;
    const int w = t >> 6;
    const int lane = t & 63;
    if (t < NBLK) lhist[t] = 0;

    const int row0 = blockIdx.x * 32;
    // wave w: ballots for rows w*8 .. w*8+7
#pragma unroll
    for (int i = 0; i < 8; ++i) {
        const int row = row0 + w * 8 + i;
        const float v = onehot[(size_t)row * NBLK + lane];   // coalesced 256B
        const unsigned long long mm = __ballot(v > 0.5f);
        const int d = (int)__ffsll(mm) - 1;
        if (lane == 0) rowd[w * 8 + i] = d;
    }
    // wave w: x->bf16 for rows w*8 .. w*8+7, 1 float4/lane/row
#pragma unroll
    for (int i = 0; i < 8; ++i) {
        const int row = row0 + w * 8 + i;
        const float4 v = ((const float4*)(x + ((size_t)row << 8)))[lane];
        ushort4 b;
        b.x = f2bf(v.x); b.y = f2bf(v.y); b.z = f2bf(v.z); b.w = f2bf(v.w);
        *(ushort4*)(xb + ((size_t)row << 8) + lane * 4) = b;  // 512B/row contiguous
    }
    __syncthreads();

    int d = 0, slot = 0;
    if (t < 32) {
        d = rowd[t];
        slot = atomicAdd(&lhist[d], 1);        // LDS atomic
    }
    __syncthreads();
    if (t < NBLK && lhist[t] > 0)              // skip zero increments
        lbase[t] = atomicAdd(&counts[t * CPAD], lhist[t]);
    __syncthreads();
    if (t < 32) buckets[d * BCAP + lbase[d] + slot] = row0 + t;
}

// 512 blocks: [task:3][d:6], d = blockIdx&63 (XCD affinity).
// task = rt*4+ct; rt in {0,1} (row-tile base rt*32, stride 64), ct in 0..3.
// Block tile: 32 bucket-rows x 64 cols; 4 waves = 4 col-slices of 16.
// No LDS, no barriers.
__global__ __launch_bounds__(256) void dd_compute(
    const unsigned short* __restrict__ xb,    // [4096, 256] bf16
    const float* __restrict__ W,              // [64, 256, 256] (d, k, col)
    const float* __restrict__ Bw,             // [64, 256]
    const int* __restrict__ counts,           // [64*CPAD]
    const int* __restrict__ buckets,          // [64, BCAP]
    float* __restrict__ out)                  // [4096, 256]
{
    const int t    = threadIdx.x;
    const int lane = t & 63;
    const int w    = t >> 6;                  // wave = col-slice
    const int d    = blockIdx.x & 63;
    const int task = blockIdx.x >> 6;         // 0..7
    const int rt   = task >> 2;               // 0..1
    const int ct   = task & 3;                // 0..3
    const int cw   = ct * 64 + w * 16;        // wave's col base
    const int m    = lane & 15;
    const int qd   = lane >> 4;

    const int cnt = counts[d * CPAD];
    if (rt * 32 >= cnt) return;               // early exit before W prologue

    // loop-invariant B fragments straight from fp32 W:
    // lane holds B[k=kb*32+qd*8+j][n=cw+m]
    const float* wb = W + ((size_t)d << 16) + (size_t)(qd * 8) * 256 + (cw + m);
    bf16x8 bfrag[8];
#pragma unroll
    for (int kb = 0; kb < 8; ++kb) {
        const float* wp = wb + (size_t)(kb * 32) * 256;
#pragma unroll
        for (int j = 0; j < 8; ++j)
            bfrag[kb][j] = (short)f2bf(wp[j * 256]);
    }

    const float bias = Bw[d * 256 + cw + m];
    const int* bkt = buckets + d * BCAP;

    for (int base = rt * 32; base < cnt; base += 64) {
        // per-lane row-id gathers (16 consecutive slots -> 1-2 lines)
        const int i0 = base + m;
        const int i1 = base + 16 + m;
        const int r0 = bkt[i0 < cnt ? i0 : cnt - 1];
        const int r1 = bkt[i1 < cnt ? i1 : cnt - 1];

        // A fragments: direct 16B bf16 loads, rows r0/r1, k = kb*32 + qd*8
        const unsigned short* xp0 = xb + ((size_t)r0 << 8) + qd * 8;
        const unsigned short* xp1 = xb + ((size_t)r1 << 8) + qd * 8;

        f32x4 acc0 = {bias, bias, bias, bias};
        f32x4 acc1 = {bias, bias, bias, bias};
#pragma unroll
        for (int kb = 0; kb < 8; ++kb) {
            bf16x8 a0 = *(const bf16x8*)(xp0 + kb * 32);
            acc0 = __builtin_amdgcn_mfma_f32_16x16x32_bf16(a0, bfrag[kb], acc0, 0, 0, 0);
        }
#pragma unroll
        for (int kb = 0; kb < 8; ++kb) {
            bf16x8 a1 = *(const bf16x8*)(xp1 + kb * 32);
            acc1 = __builtin_amdgcn_mfma_f32_16x16x32_bf16(a1, bfrag[kb], acc1, 0, 0, 0);
        }

        // stores: C/D row = qd*4+reg, col = m; re-gather rids (L1-hot)
#pragma unroll
        for (int reg = 0; reg < 4; ++reg) {
            const int rl0 = base + qd * 4 + reg;
            if (rl0 < cnt) {
                const int rr = bkt[rl0];
                out[((size_t)rr << 8) + cw + m] = acc0[reg];
            }
            const int rl1 = base + 16 + qd * 4 + reg;
            if (rl1 < cnt) {
                const int rr = bkt[rl1];
                out[((size_t)rr << 8) + cw + m] = acc1[reg];
            }
        }
    }
}

extern "C" void kernel_launch(void* const* d_in, const int* in_sizes, int n_in,
                              void* d_out, int out_size, void* d_ws, size_t ws_size,
                              hipStream_t stream) {
    const float* x      = (const float*)d_in[0];   // [4096, 256]
    const float* onehot = (const float*)d_in[1];   // [4096, 64]
    const float* W      = (const float*)d_in[2];   // [64, 256, 256]
    const float* Bw     = (const float*)d_in[3];   // [64, 256]
    float* out = (float*)d_out;                    // [4096, 256]

    // ws layout: counts 4KB | buckets 256KB | xb 2MB
    int* counts  = (int*)d_ws;
    int* buckets = (int*)((char*)d_ws + NBLK * CPAD * 4);
    unsigned short* xb = (unsigned short*)((char*)d_ws + NBLK * CPAD * 4 + NBLK * BCAP * 4);

    hipMemsetAsync(counts, 0, NBLK * CPAD * sizeof(int), stream);
    dd_prep<<<128, 256, 0, stream>>>(x, onehot, counts, buckets, xb);
    dd_compute<<<512, 256, 0, stream>>>(xb, W, Bw, counts, buckets, out);
}

// Round 11
// 85.761 us; speedup vs baseline: 1.0534x; 1.0315x over previous
//
#include <hip/hip_runtime.h>

// DisjointDense: out[b] = x[b] @ W[sel[b]] + Bw[sel[b]]
// B=4096, D_IN=256, D_OUT=256, N_DISJOINT=64, all fp32.
//
// R11 = exact R8 revert (best measured: 85.9us). R9 (CAS-zeroing, prep@256)
// and R10 (compute grid 512) both regressed with understood mechanisms:
//  - CAS storm: 16K device-scope CAS on 64 lines = cross-XCD serialization.
//  - 512-grid: coarser row-stride worsens bucket-size load imbalance and
//    halves live waves/CU in a gather-latency-bound kernel.
// Structure: memset(4KB) + dd_prep (bucketize + x->bf16) + dd_compute
// (LDS-free barrier-free MFMA gather; B-frags loop-invariant from fp32 W;
// XCD affinity d = blockIdx&63 keeps W[d] L2-resident).

#define NBLK 64
#define BCAP 1024
#define CPAD 16

typedef __attribute__((ext_vector_type(8))) short bf16x8;
typedef __attribute__((ext_vector_type(4))) float f32x4;

__device__ __forceinline__ unsigned short f2bf(float f) {
    unsigned u = __float_as_uint(f);
    u += 0x7FFFu + ((u >> 16) & 1u);       // round-to-nearest-even
    return (unsigned short)(u >> 16);
}

// 128 blocks x 256 threads; block handles 32 rows: bucketize + x->bf16.
__global__ __launch_bounds__(256) void dd_prep(
    const float* __restrict__ x,        // [4096, 256]
    const float* __restrict__ onehot,   // [4096, 64]
    int* __restrict__ counts,           // [64*CPAD], pre-zeroed
    int* __restrict__ buckets,          // [64, BCAP]
    unsigned short* __restrict__ xb)    // [4096, 256] bf16
{
    __shared__ int rowd[32];
    __shared__ int lhist[NBLK];
    __shared__ int lbase[NBLK];
    const int t = threadIdx.x;
    const int w = t >> 6;
    const int lane = t & 63;
    if (t < NBLK) lhist[t] = 0;

    const int row0 = blockIdx.x * 32;
    // wave w: ballots for rows w*8 .. w*8+7
#pragma unroll
    for (int i = 0; i < 8; ++i) {
        const int row = row0 + w * 8 + i;
        const float v = onehot[(size_t)row * NBLK + lane];   // coalesced 256B
        const unsigned long long mm = __ballot(v > 0.5f);
        const int d = (int)__ffsll(mm) - 1;
        if (lane == 0) rowd[w * 8 + i] = d;
    }
    // wave w: x->bf16 for rows w*8 .. w*8+7, 1 float4/lane/row
#pragma unroll
    for (int i = 0; i < 8; ++i) {
        const int row = row0 + w * 8 + i;
        const float4 v = ((const float4*)(x + ((size_t)row << 8)))[lane];
        ushort4 b;
        b.x = f2bf(v.x); b.y = f2bf(v.y); b.z = f2bf(v.z); b.w = f2bf(v.w);
        *(ushort4*)(xb + ((size_t)row << 8) + lane * 4) = b;  // 512B/row contiguous
    }
    __syncthreads();

    int d = 0, slot = 0;
    if (t < 32) {
        d = rowd[t];
        slot = atomicAdd(&lhist[d], 1);        // LDS atomic
    }
    __syncthreads();
    if (t < NBLK && lhist[t] > 0)              // skip zero increments
        lbase[t] = atomicAdd(&counts[t * CPAD], lhist[t]);
    __syncthreads();
    if (t < 32) buckets[d * BCAP + lbase[d] + slot] = row0 + t;
}

// 1024 blocks: [task:4][d:6], d = blockIdx&63 (XCD affinity).
// task: rt = task>>2 (row tile, base rt*32, stride 128), ct = task&3.
// Block tile: 32 bucket-rows x 64 cols; 4 waves = 4 col-slices of 16.
// No LDS, no barriers.
__global__ __launch_bounds__(256) void dd_compute(
    const unsigned short* __restrict__ xb,    // [4096, 256] bf16
    const float* __restrict__ W,              // [64, 256, 256] (d, k, col)
    const float* __restrict__ Bw,             // [64, 256]
    const int* __restrict__ counts,           // [64*CPAD]
    const int* __restrict__ buckets,          // [64, BCAP]
    float* __restrict__ out)                  // [4096, 256]
{
    const int t    = threadIdx.x;
    const int lane = t & 63;
    const int w    = t >> 6;                  // wave = col-slice
    const int d    = blockIdx.x & 63;
    const int task = blockIdx.x >> 6;         // 0..15
    const int rt   = task >> 2;               // 0..3
    const int ct   = task & 3;                // 0..3
    const int cw   = ct * 64 + w * 16;        // wave's col base
    const int m    = lane & 15;
    const int qd   = lane >> 4;

    const int cnt = counts[d * CPAD];
    if (rt * 32 >= cnt) return;               // early exit before W prologue

    // loop-invariant B fragments straight from fp32 W:
    // lane holds B[k=kb*32+qd*8+j][n=cw+m]
    const float* wb = W + ((size_t)d << 16) + (size_t)(qd * 8) * 256 + (cw + m);
    bf16x8 bfrag[8];
#pragma unroll
    for (int kb = 0; kb < 8; ++kb) {
        const float* wp = wb + (size_t)(kb * 32) * 256;
#pragma unroll
        for (int j = 0; j < 8; ++j)
            bfrag[kb][j] = (short)f2bf(wp[j * 256]);
    }

    const float bias = Bw[d * 256 + cw + m];
    const int* bkt = buckets + d * BCAP;

    for (int base = rt * 32; base < cnt; base += 128) {
        // per-lane row-id gathers (16 consecutive slots -> 1-2 lines)
        const int i0 = base + m;
        const int i1 = base + 16 + m;
        const int r0 = bkt[i0 < cnt ? i0 : cnt - 1];
        const int r1 = bkt[i1 < cnt ? i1 : cnt - 1];

        // A fragments: direct 16B bf16 loads, rows r0/r1, k = kb*32 + qd*8
        const unsigned short* xp0 = xb + ((size_t)r0 << 8) + qd * 8;
        const unsigned short* xp1 = xb + ((size_t)r1 << 8) + qd * 8;

        f32x4 acc0 = {bias, bias, bias, bias};
        f32x4 acc1 = {bias, bias, bias, bias};
#pragma unroll
        for (int kb = 0; kb < 8; ++kb) {
            bf16x8 a0 = *(const bf16x8*)(xp0 + kb * 32);
            acc0 = __builtin_amdgcn_mfma_f32_16x16x32_bf16(a0, bfrag[kb], acc0, 0, 0, 0);
        }
#pragma unroll
        for (int kb = 0; kb < 8; ++kb) {
            bf16x8 a1 = *(const bf16x8*)(xp1 + kb * 32);
            acc1 = __builtin_amdgcn_mfma_f32_16x16x32_bf16(a1, bfrag[kb], acc1, 0, 0, 0);
        }

        // stores: C/D row = qd*4+reg, col = m; re-gather rids (L1-hot)
#pragma unroll
        for (int reg = 0; reg < 4; ++reg) {
            const int rl0 = base + qd * 4 + reg;
            if (rl0 < cnt) {
                const int rr = bkt[rl0];
                out[((size_t)rr << 8) + cw + m] = acc0[reg];
            }
            const int rl1 = base + 16 + qd * 4 + reg;
            if (rl1 < cnt) {
                const int rr = bkt[rl1];
                out[((size_t)rr << 8) + cw + m] = acc1[reg];
            }
        }
    }
}

extern "C" void kernel_launch(void* const* d_in, const int* in_sizes, int n_in,
                              void* d_out, int out_size, void* d_ws, size_t ws_size,
                              hipStream_t stream) {
    const float* x      = (const float*)d_in[0];   // [4096, 256]
    const float* onehot = (const float*)d_in[1];   // [4096, 64]
    const float* W      = (const float*)d_in[2];   // [64, 256, 256]
    const float* Bw     = (const float*)d_in[3];   // [64, 256]
    float* out = (float*)d_out;                    // [4096, 256]

    // ws layout: counts 4KB | buckets 256KB | xb 2MB
    int* counts  = (int*)d_ws;
    int* buckets = (int*)((char*)d_ws + NBLK * CPAD * 4);
    unsigned short* xb = (unsigned short*)((char*)d_ws + NBLK * CPAD * 4 + NBLK * BCAP * 4);

    hipMemsetAsync(counts, 0, NBLK * CPAD * sizeof(int), stream);
    dd_prep<<<128, 256, 0, stream>>>(x, onehot, counts, buckets, xb);
    dd_compute<<<1024, 256, 0, stream>>>(xb, W, Bw, counts, buckets, out);
}